// Round 17
// baseline (124.767 us; speedup 1.0000x reference)
//
#include <hip/hip_runtime.h>
#include <hip/hip_bf16.h>
#include <math.h>

// SpectralConv2d (FNO): B=16, Cin=Cout=32, H=W=256, MODES=16x16.
// Grid 1024 (bi/bo x 2 w-halves) = 4 blocks/CU = 16 waves/CU, with DS-free
// main loops (2-register twiddle power-chain: r = R1^m, R1 *= S1 per h).
// This is R4's occupancy with R8's DS-free loops — the untested quadrant.
//  kF (bi,wq): T[m][wl] = sum_h x[h][wq*128+wl] e^{-2pi i m h/256} (radix-2),
//              xsubp[wq][bi][m,n] = sum_wl T[m][wl] e^{-2pi i n (wq*128+wl)/256}
//  kI (bo,wq): os = sum_i (xsubp[0]+xsubp[1])*W ; U[m][wl] for this half;
//              y[h][wq*128+wl] = (1/65536) Re(sum_m U e^{+2pi i m h/256})

#define PI_F 3.14159265358979323846f

__global__ __launch_bounds__(256, 4) void kF(const float* __restrict__ x,
                                             float2* __restrict__ xsubp) {
    __shared__ float2 tw[256];           // 2 KB
    __shared__ float2 Ts[16][130];       // 16.6 KB, padded row (130)
    __shared__ float4 red[4][4][64];     // 16 KB
    const int t = threadIdx.x;
    { float ang = (2.0f * PI_F / 256.0f) * (float)t;
      tw[t] = make_float2(__cosf(ang), __sinf(ang)); }
    __syncthreads();

    const int bi = blockIdx.x >> 1, wq = blockIdx.x & 1;
    const float* xp = x + (size_t)bi * 65536 + wq * 128;
    const int l = t & 63, wv = t >> 6;   // lane: cols 2l,2l+1; wave: h-chunk
    const int h0 = wv * 32;

    float Tr0[16], Ti0[16], Tr1[16], Ti1[16];
#pragma unroll
    for (int m = 0; m < 16; ++m) { Tr0[m] = Ti0[m] = Tr1[m] = Ti1[m] = 0.0f; }

    // R1 = e^{-2pi i h/256} (wave-uniform), S1 = e^{-2pi i/256}
    float R1r = tw[h0].x, R1i = -tw[h0].y;
    const float S1r = tw[1].x, S1i = -tw[1].y;

    for (int j = 0; j < 32; ++j) {
        const int h = h0 + j;            // h-pair (h, h+128)
        const float2 v0 = ((const float2*)(xp + h * 256))[l];
        const float2 v1 = ((const float2*)(xp + (h + 128) * 256))[l];
        const float xe0 = v0.x + v1.x, xe1 = v0.y + v1.y;
        const float xo0 = v0.x - v1.x, xo1 = v0.y - v1.y;
        float rr = 1.0f, ri = 0.0f;      // r = R1^m
#pragma unroll
        for (int m = 0; m < 16; ++m) {
            const float a = (m & 1) ? xo0 : xe0;
            const float b = (m & 1) ? xo1 : xe1;
            Tr0[m] = fmaf(a, rr, Tr0[m]); Ti0[m] = fmaf(a, ri, Ti0[m]);
            Tr1[m] = fmaf(b, rr, Tr1[m]); Ti1[m] = fmaf(b, ri, Ti1[m]);
            const float nr = fmaf(rr, R1r, -ri * R1i);   // r *= R1
            ri = fmaf(rr, R1i, ri * R1r); rr = nr;
        }
        const float nR = fmaf(R1r, S1r, -R1i * S1i);     // R1 *= S1
        R1i = fmaf(R1r, S1i, R1i * S1r); R1r = nR;
    }

    // cross-wave reduce into Ts, 4 m-groups of 4
#pragma unroll
    for (int mg = 0; mg < 4; ++mg) {
        if (mg) __syncthreads();
#pragma unroll
        for (int mm = 0; mm < 4; ++mm) {
            const int m = mg * 4 + mm;
            red[wv][mm][l] = make_float4(Tr0[m], Ti0[m], Tr1[m], Ti1[m]);
        }
        __syncthreads();
        const int mm = t >> 6, idx = t & 63;
        float4 a0 = red[0][mm][idx], a1 = red[1][mm][idx];
        float4 a2 = red[2][mm][idx], a3 = red[3][mm][idx];
        *(float4*)&Ts[mg * 4 + mm][2 * idx] =
            make_float4(a0.x + a1.x + a2.x + a3.x, a0.y + a1.y + a2.y + a3.y,
                        a0.z + a1.z + a2.z + a3.z, a0.w + a1.w + a2.w + a3.w);
    }
    __syncthreads();

    // w-DFT tail over this half (actual w = wq*128 + wl), rotation recurrence
    const int m = t >> 4, n = t & 15;
    const float c1 = tw[n].x, s1 = tw[n].y;
    float cr = ((n & 1) && wq) ? -1.0f : 1.0f, ci = 0.0f;  // (-1)^{n*wq}
    float ar = 0.0f, ai = 0.0f;
    for (int w = 0; w < 128; ++w) {
        float2 Tv = Ts[m][w];            // 4 bcast groups/wave, distinct banks
        ar += Tv.x * cr + Tv.y * ci;     // * e^{-i n w}
        ai += Tv.y * cr - Tv.x * ci;
        const float nr = fmaf(cr, c1, -ci * s1);
        const float nc = fmaf(cr, s1, ci * c1);
        cr = nr; ci = nc;
    }
    xsubp[((size_t)(wq * 512 + bi)) * 256 + t] = make_float2(ar, ai);
}

__global__ __launch_bounds__(256, 4) void kI(const float2* __restrict__ xsubp,
                                             const float* __restrict__ wr,
                                             const float* __restrict__ wi,
                                             float* __restrict__ y) {
    __shared__ float2 tw[256];           // 2 KB
    __shared__ float2 os[256];           // 2 KB
    __shared__ float2 U[16][130];        // 16.6 KB
    const int t = threadIdx.x;
    { float ang = (2.0f * PI_F / 256.0f) * (float)t;
      tw[t] = make_float2(__cosf(ang), __sinf(ang)); }

    const int bo = blockIdx.x >> 1, wq = blockIdx.x & 1;
    const int b = bo >> 5, o = bo & 31;

    // stage 1: channel mix over Cin (sum the two w-half partials)
    {
        const float2* xa = xsubp + (size_t)(b * 32) * 256 + t;
        const float2* xb = xa + (size_t)512 * 256;
        const float* wrp = wr + (size_t)o * 256 + t;
        const float* wip = wi + (size_t)o * 256 + t;
        float ar = 0.f, ai = 0.f;
#pragma unroll 8
        for (int i = 0; i < 32; ++i) {
            float2 p = xa[i * 256];
            float2 q = xb[i * 256];
            float xr = p.x + q.x, xi2 = p.y + q.y;
            float wre = wrp[i * 8192];
            float wim = wip[i * 8192];
            ar += xr * wre - xi2 * wim;
            ai += xr * wim + xi2 * wre;
        }
        os[t] = make_float2(ar, ai);
    }
    __syncthreads();

    // stage 2: U[m][wl] for this half; threads (mh = t>>7, wl = t&127)
    {
        const int wl = t & 127, mh = t >> 7;
        const int w = wq * 128 + wl;
        float twr[16], twi[16];
#pragma unroll
        for (int n = 0; n < 16; ++n) {
            float2 cs = tw[(n * w) & 255];
            twr[n] = cs.x; twi[n] = cs.y;
        }
#pragma unroll
        for (int mm = 0; mm < 8; ++mm) {
            const int m = mh * 8 + mm;
            float ur = 0.f, ui = 0.f;
#pragma unroll
            for (int n = 0; n < 16; ++n) {
                float2 ov = os[m * 16 + n];          // uniform -> broadcast
                ur += ov.x * twr[n] - ov.y * twi[n]; // * e^{+i n w}
                ui += ov.x * twi[n] + ov.y * twr[n];
            }
            U[m][wl] = make_float2(ur, ui);
        }
    }
    __syncthreads();

    // stage 3: inverse h-DFT (radix-2 over h), lane owns cols 2l,2l+1;
    // twiddles via 2-register power chain (DS-free loop)
    const int l = t & 63, wv = t >> 6;
    const int h0 = wv * 32;
    float Ur0[16], Ui0[16], Ur1[16], Ui1[16];
#pragma unroll
    for (int m = 0; m < 16; ++m) {
        float4 p = *(const float4*)&U[m][2 * l];
        Ur0[m] = p.x; Ui0[m] = p.y; Ur1[m] = p.z; Ui1[m] = p.w;
    }
    float R1r = tw[h0].x, R1i = tw[h0].y;    // e^{+2pi i h/256}
    const float S1r = tw[1].x, S1i = tw[1].y;

    float* yp = y + (size_t)bo * 65536 + wq * 128;
    const float inv = 1.0f / 65536.0f;
    for (int j = 0; j < 32; ++j) {
        const int h = h0 + j;            // h-pair (h, h+128)
        float ae0 = 0.f, ae1 = 0.f, ao0 = 0.f, ao1 = 0.f;
        float rr = 1.0f, ri = 0.0f;      // r = R1^m
#pragma unroll
        for (int m = 0; m < 16; ++m) {
            const float va = fmaf(Ur0[m], rr, -(Ui0[m] * ri));  // Re(U e^{+ia})
            const float vb = fmaf(Ur1[m], rr, -(Ui1[m] * ri));
            if (m & 1) { ao0 += va; ao1 += vb; }
            else       { ae0 += va; ae1 += vb; }
            const float nr = fmaf(rr, R1r, -ri * R1i);          // r *= R1
            ri = fmaf(rr, R1i, ri * R1r); rr = nr;
        }
        const float nR = fmaf(R1r, S1r, -R1i * S1i);            // R1 *= S1
        R1i = fmaf(R1r, S1i, R1i * S1r); R1r = nR;

        ((float2*)(yp + h * 256))[l] =
            make_float2((ae0 + ao0) * inv, (ae1 + ao1) * inv);
        ((float2*)(yp + (h + 128) * 256))[l] =
            make_float2((ae0 - ao0) * inv, (ae1 - ao1) * inv);
    }
}

extern "C" void kernel_launch(void* const* d_in, const int* in_sizes, int n_in,
                              void* d_out, int out_size, void* d_ws, size_t ws_size,
                              hipStream_t stream) {
    const float* x  = (const float*)d_in[0];   // [16][32][256][256]
    const float* wr = (const float*)d_in[1];   // [32][32][16][16]
    const float* wi = (const float*)d_in[2];   // [32][32][16][16]
    float* y = (float*)d_out;                  // [16][32][256][256]

    float2* xsubp = (float2*)d_ws;             // [2][512][256] float2 = 2 MB

    kF<<<1024, 256, 0, stream>>>(x, xsubp);
    kI<<<1024, 256, 0, stream>>>(xsubp, wr, wi, y);
}